// Round 5
// baseline (137.523 us; speedup 1.0000x reference)
//
#include <hip/hip_runtime.h>
#include <math.h>

#define NL 5
#define KM 5
#define MF 50
#define BATCH_ 131072
#define XROW (NL + 2*MF)      /* 105 */
#define SROW (KM*(2*NL+1))    /* 55  */
#define LOG2PI_F 1.8378770664093453f

#define BPB 64                    /* batches per block, 4 lanes per batch */
#define NB_FUSED (BATCH_/BPB)     /* 2048 */
#define NB_MONO  (BATCH_/256)     /* 512  */

typedef float v2f __attribute__((ext_vector_type(2)));

__device__ __forceinline__ float rcpf_(float x)  { return __builtin_amdgcn_rcpf(x); }
__device__ __forceinline__ float sqrtf_(float x) { return __builtin_amdgcn_sqrtf(x); }
__device__ __forceinline__ float exp_(float x)   { return __expf(x); }
__device__ __forceinline__ float log_(float x)   { return __logf(x); }

// ndtr via A&S 7.1.26 erf (|eps| <= 1.5e-7)
__device__ __forceinline__ float ndtr_f(float x) {
    float z = fabsf(x) * 0.70710678f;
    float t = rcpf_(fmaf(0.3275911f, z, 1.0f));
    float poly = t*(0.254829592f + t*(-0.284496736f + t*(1.421413741f +
                 t*(-1.453152027f + t*1.061405429f))));
    float h = 0.5f * poly * exp_(-z*z);
    return x >= 0.0f ? 1.0f - h : h;
}

// packed 2-wide ndtr: identical per-component math, poly/setup become v_pk_fma
__device__ __forceinline__ v2f ndtr2_f(v2f x) {
    v2f z = {fabsf(x.x), fabsf(x.y)};
    z = z * 0.70710678f;
    v2f td = 0.3275911f * z + 1.0f;
    v2f t  = {rcpf_(td.x), rcpf_(td.y)};
    v2f poly = t*(0.254829592f + t*(-0.284496736f + t*(1.421413741f +
               t*(-1.453152027f + t*1.061405429f))));
    v2f zz = z * z;
    v2f e  = {exp_(-zz.x), exp_(-zz.y)};
    v2f h  = 0.5f * poly * e;
    v2f r;
    r.x = x.x >= 0.0f ? 1.0f - h.x : h.x;
    r.y = x.y >= 0.0f ? 1.0f - h.y : h.y;
    return r;
}

// ndtri via Giles' erfinv. Caller overrides exact endpoints.
__device__ __forceinline__ float ndtri_f(float p) {
    float x = fmaf(2.0f, p, -1.0f);
    float w = -log_((1.0f - x) * (1.0f + x));
    float wc = w - 2.5f;
    float pc =            2.81022636e-08f;
    pc = fmaf(pc, wc,     3.43273939e-07f);
    pc = fmaf(pc, wc,    -3.5233877e-06f);
    pc = fmaf(pc, wc,    -4.39150654e-06f);
    pc = fmaf(pc, wc,     0.00021858087f);
    pc = fmaf(pc, wc,    -0.00125372503f);
    pc = fmaf(pc, wc,    -0.00417768164f);
    pc = fmaf(pc, wc,     0.246640727f);
    pc = fmaf(pc, wc,     1.50140941f);
    float wt = sqrtf_(w) - 3.0f;
    float pt =           -0.000200214257f;
    pt = fmaf(pt, wt,     0.000100950558f);
    pt = fmaf(pt, wt,     0.00134934322f);
    pt = fmaf(pt, wt,    -0.00367342844f);
    pt = fmaf(pt, wt,     0.00573950773f);
    pt = fmaf(pt, wt,    -0.0076224613f);
    pt = fmaf(pt, wt,     0.00943887047f);
    pt = fmaf(pt, wt,     1.00167406f);
    pt = fmaf(pt, wt,     2.83297682f);
    float r = (w < 5.0f) ? pc : pt;
    return 1.41421356f * r * x;
}

// octant-reduced atan2, degree-11 odd minimax (~1e-6 rad)
__device__ __forceinline__ float atan2_f(float y, float x) {
    float ax = fabsf(x), ay = fabsf(y);
    float mx = fmaxf(ax, ay), mn = fminf(ax, ay);
    float a = mn * rcpf_(mx);
    float s = a * a;
    float r =            -0.01172120f;
    r = fmaf(r, s,        0.05265332f);
    r = fmaf(r, s,       -0.11643287f);
    r = fmaf(r, s,        0.19354346f);
    r = fmaf(r, s,       -0.33262347f);
    r = fmaf(r, s,        0.99997726f);
    r = r * a;
    r = (ay > ax)   ? (1.5707964f - r) : r;
    r = (x < 0.0f)  ? (3.1415927f - r) : r;
    return (y < 0.0f) ? -r : r;
}

// ---------- scalar forward model, DIVISION-FREE recursion ----------
// Track Z = n/d (complex). The layer impedance is COMPLEX: zeta = wj*(1+i).
// Per layer:  u = zeta*d + n ; v = zeta*d - n ; w = E*v
//             n' = zeta*(u-w) ; d' = u+w
// where zeta*d = wj*((dR-dC) + i(dR+dC)).
// Division folds into epilogue: absZ2 = |n|^2/|d|^2, angle from n*conj(d).
__device__ __forceinline__ float fwd_eval(float c5, float sw, float oA, float oP,
                                          const float pr[9])
{
    float z0 = sw * pr[0];
    float nR = z0, nC = z0;
    float dR = 1.0f, dC = 0.0f;
    #pragma unroll
    for (int j = NL-2; j >= 0; --j) {
        float wj = sw * pr[5+j];
        float t  = sw * pr[1+j];
        float t2 = t * t, t3 = t2 * t;
        float ejR = (1.0f - t) + t3 * fmaf(-0.16666667f, t, 0.33333334f);
        float ejC = fmaf(t3, -0.33333334f, t2) - t;
        float pRz = wj * (dR - dC);        // Re(zeta*d)
        float pCz = wj * (dR + dC);        // Im(zeta*d)
        float uR = pRz + nR, uC = pCz + nC;
        float vR = pRz - nR, vC = pCz - nC;
        float wR = fmaf(ejR, vR, -ejC*vC);
        float wC = fmaf(ejR, vC,  ejC*vR);
        float aR = uR - wR, aC = uC - wC;
        nR = wj * (aR - aC);               // zeta*(u-w)
        nC = wj * (aR + aC);
        dR = uR + wR;
        dC = uC + wC;
    }
    float n2 = fmaf(nR, nR, nC*nC);
    float d2 = fmaf(dR, dR, dC*dC);
    float absZ2 = n2 * rcpf_(d2);
    float mR = fmaf(nR, dR,  nC*dC);
    float mC = fmaf(nC, dR, -nR*dC);
    float aRes  = fmaf(0.43429448f, log_(absZ2), c5);
    float ph    = atan2_f(mC, mR);
    float ap    = fabsf(aRes * ph);
    float invp  = rcpf_(ap);
    float vA = (aRes - oA) * (33.333332f * fabsf(ph)   * invp);
    float vP = (ph   - oP) * (33.333332f * fabsf(aRes) * invp);
    return fmaf(-0.5f, vA*vA, fmaf(-0.5f, vP*vP, 5.1752387f - log_(ap)));
}

// ---------- packed forward model: TWO INDEPENDENT FREQUENCIES per call ------
__device__ __forceinline__ float fwd_eval2(v2f c5, v2f sw, v2f oA, v2f oP,
                                           const float pr[9])
{
    v2f z0 = sw * pr[0];
    v2f nR = z0, nC = z0;
    v2f dR = {1.0f, 1.0f}, dC = {0.0f, 0.0f};
    #pragma unroll
    for (int j = NL-2; j >= 0; --j) {
        v2f wj = sw * pr[5+j];
        v2f t  = sw * pr[1+j];
        v2f t2 = t * t, t3 = t2 * t;
        v2f ejR = (1.0f - t) + t3 * (0.33333334f - 0.16666667f * t);
        v2f ejC = t2 - 0.33333334f * t3 - t;
        v2f pRz = wj * (dR - dC);
        v2f pCz = wj * (dR + dC);
        v2f uR = pRz + nR, uC = pCz + nC;
        v2f vR = pRz - nR, vC = pCz - nC;
        v2f wR = ejR*vR - ejC*vC;
        v2f wC = ejR*vC + ejC*vR;
        v2f aR = uR - wR, aC = uC - wC;
        nR = wj * (aR - aC);
        nC = wj * (aR + aC);
        dR = uR + wR;
        dC = uC + wC;
    }
    v2f n2 = nR*nR + nC*nC;
    v2f d2 = dR*dR + dC*dC;
    v2f id2 = {rcpf_(d2.x), rcpf_(d2.y)};
    v2f absZ2 = n2 * id2;
    v2f mR = nR*dR + nC*dC;
    v2f mC = nC*dR - nR*dC;
    v2f aRes = {fmaf(0.43429448f, log_(absZ2.x), c5.x),
                fmaf(0.43429448f, log_(absZ2.y), c5.y)};
    v2f ph   = {atan2_f(mC.x, mR.x), atan2_f(mC.y, mR.y)};
    v2f prod = aRes * ph;
    v2f ap   = {fabsf(prod.x), fabsf(prod.y)};
    v2f invp = {rcpf_(ap.x), rcpf_(ap.y)};
    v2f aph  = {fabsf(ph.x),   fabsf(ph.y)};
    v2f aar  = {fabsf(aRes.x), fabsf(aRes.y)};
    v2f vA = (aRes - oA) * (33.333332f * aph * invp);
    v2f vP = (ph   - oP) * (33.333332f * aar * invp);
    v2f res = (v2f){5.1752387f - log_(ap.x), 5.1752387f - log_(ap.y)}
              - 0.5f*vA*vA - 0.5f*vP*vP;
    return res.x + res.y;
}

// ---------- 2x2: TWO independent pair-evals advanced in lockstep ----------
// Forces 2-way ILP through the serial layer recursion + trans epilogue,
// which the post-RA scheduler cannot achieve across two ~200-inst bodies.
__device__ __forceinline__ float fwd_eval2x2(
    v2f c5a, v2f swa, v2f oAa, v2f oPa,
    v2f c5b, v2f swb, v2f oAb, v2f oPb,
    const float pr[9])
{
    v2f z0a = swa * pr[0];
    v2f z0b = swb * pr[0];
    v2f nRa = z0a, nCa = z0a, dRa = {1.0f,1.0f}, dCa = {0.0f,0.0f};
    v2f nRb = z0b, nCb = z0b, dRb = {1.0f,1.0f}, dCb = {0.0f,0.0f};
    #pragma unroll
    for (int j = NL-2; j >= 0; --j) {
        float p5 = pr[5+j], p1 = pr[1+j];
        v2f wja = swa * p5;            v2f wjb = swb * p5;
        v2f ta  = swa * p1;            v2f tb  = swb * p1;
        v2f t2a = ta * ta;             v2f t2b = tb * tb;
        v2f t3a = t2a * ta;            v2f t3b = t2b * tb;
        v2f ejRa = (1.0f - ta) + t3a * (0.33333334f - 0.16666667f * ta);
        v2f ejRb = (1.0f - tb) + t3b * (0.33333334f - 0.16666667f * tb);
        v2f ejCa = t2a - 0.33333334f * t3a - ta;
        v2f ejCb = t2b - 0.33333334f * t3b - tb;
        v2f pRa = wja * (dRa - dCa);   v2f pRb = wjb * (dRb - dCb);
        v2f pCa = wja * (dRa + dCa);   v2f pCb = wjb * (dRb + dCb);
        v2f uRa = pRa + nRa;           v2f uRb = pRb + nRb;
        v2f uCa = pCa + nCa;           v2f uCb = pCb + nCb;
        v2f vRa = pRa - nRa;           v2f vRb = pRb - nRb;
        v2f vCa = pCa - nCa;           v2f vCb = pCb - nCb;
        v2f wRa = ejRa*vRa - ejCa*vCa; v2f wRb = ejRb*vRb - ejCb*vCb;
        v2f wCa = ejRa*vCa + ejCa*vRa; v2f wCb = ejRb*vCb + ejCb*vRb;
        v2f aRa = uRa - wRa;           v2f aRb = uRb - wRb;
        v2f aCa = uCa - wCa;           v2f aCb = uCb - wCb;
        nRa = wja * (aRa - aCa);       nRb = wjb * (aRb - aCb);
        nCa = wja * (aRa + aCa);       nCb = wjb * (aRb + aCb);
        dRa = uRa + wRa;               dRb = uRb + wRb;
        dCa = uCa + wCa;               dCb = uCb + wCb;
    }
    v2f n2a = nRa*nRa + nCa*nCa;       v2f n2b = nRb*nRb + nCb*nCb;
    v2f d2a = dRa*dRa + dCa*dCa;       v2f d2b = dRb*dRb + dCb*dCb;
    v2f id2a = {rcpf_(d2a.x), rcpf_(d2a.y)};
    v2f id2b = {rcpf_(d2b.x), rcpf_(d2b.y)};
    v2f absZ2a = n2a * id2a;           v2f absZ2b = n2b * id2b;
    v2f mRa = nRa*dRa + nCa*dCa;       v2f mRb = nRb*dRb + nCb*dCb;
    v2f mCa = nCa*dRa - nRa*dCa;       v2f mCb = nCb*dRb - nRb*dCb;
    v2f aResa = {fmaf(0.43429448f, log_(absZ2a.x), c5a.x),
                 fmaf(0.43429448f, log_(absZ2a.y), c5a.y)};
    v2f aResb = {fmaf(0.43429448f, log_(absZ2b.x), c5b.x),
                 fmaf(0.43429448f, log_(absZ2b.y), c5b.y)};
    v2f pha = {atan2_f(mCa.x, mRa.x), atan2_f(mCa.y, mRa.y)};
    v2f phb = {atan2_f(mCb.x, mRb.x), atan2_f(mCb.y, mRb.y)};
    v2f proda = aResa * pha;           v2f prodb = aResb * phb;
    v2f apa = {fabsf(proda.x), fabsf(proda.y)};
    v2f apb = {fabsf(prodb.x), fabsf(prodb.y)};
    v2f invpa = {rcpf_(apa.x), rcpf_(apa.y)};
    v2f invpb = {rcpf_(apb.x), rcpf_(apb.y)};
    v2f apha = {fabsf(pha.x),   fabsf(pha.y)};
    v2f aphb = {fabsf(phb.x),   fabsf(phb.y)};
    v2f aara = {fabsf(aResa.x), fabsf(aResa.y)};
    v2f aarb = {fabsf(aResb.x), fabsf(aResb.y)};
    v2f vAa = (aResa - oAa) * (33.333332f * apha * invpa);
    v2f vAb = (aResb - oAb) * (33.333332f * aphb * invpb);
    v2f vPa = (pha   - oPa) * (33.333332f * aara * invpa);
    v2f vPb = (phb   - oPb) * (33.333332f * aarb * invpb);
    v2f resa = (v2f){5.1752387f - log_(apa.x), 5.1752387f - log_(apa.y)}
               - 0.5f*vAa*vAa - 0.5f*vPa*vPa;
    v2f resb = (v2f){5.1752387f - log_(apb.x), 5.1752387f - log_(apb.y)}
               - 0.5f*vAb*vAb - 0.5f*vPb*vPb;
    return (resa.x + resa.y) + (resb.x + resb.y);
}

// ---------------- fused kernel (prep + packed fwd, 2-deep ILP) --------------
// prep: all 256 threads, 4 lanes/batch (2 layer-reps per lane), 64 batches
// fwd : lane i handles pairs (i+4k, i+4k+25), k<6, as 3 quad-evals
//       {k, k+3}; uniform tail pair (24,49) on wave 0.
__global__ void __launch_bounds__(256, 4) k_bnn(
    const float* __restrict__ x, const float* __restrict__ s,
    const float* __restrict__ u_cat, const float* __restrict__ u_trunc,
    float* __restrict__ p_ll, float* __restrict__ p_lq)
{
    __shared__ float lds_pr[BPB][12];
    __shared__ float red0[4], red1[4];

    unsigned tid = threadIdx.x;
    unsigned bl = tid >> 2;               // 0..63
    unsigned i  = tid & 3;
    unsigned b  = blockIdx.x * BPB + bl;
    const float* srow = s + (size_t)b * SROW;
    float lqv = 0.0f;

    // --- batch-common (duplicated 4x per batch) ---
    float pro[KM];
    float sqsum = 0.0f;
    #pragma unroll
    for (int k = 0; k < KM; ++k) {
        float v = srow[k*11 + 10];
        pro[k] = v * v;
        sqsum += pro[k];
    }
    float isq = rcpf_(sqsum);
    #pragma unroll
    for (int k = 0; k < KM; ++k) pro[k] *= isq;
    float u = u_cat[b];
    float cum = 0.0f; int cnt = 0;
    #pragma unroll
    for (int k = 0; k < KM; ++k) { cum += pro[k]; if (u > cum) ++cnt; }
    int comp = cnt < KM-1 ? cnt : KM-1;

    // --- per-layer cells: rep 0 -> layer i, rep 1 -> layer i+4 (lane 0) ---
    float cacc[KM];
    #pragma unroll
    for (int k = 0; k < KM; ++k) cacc[k] = 0.0f;

    #pragma unroll
    for (int r = 0; r < 2; ++r) {
        unsigned layer = i + 4u*r;
        bool active = (layer < NL);
        unsigned ll_ = active ? layer : i;
        float lc[KM], sg[KM];
        #pragma unroll
        for (int k = 0; k < KM; ++k) {
            lc[k] = 4.0f * rcpf_(1.0f + exp_(-srow[k*11 + ll_]));
            float sv = srow[k*11 + 5 + ll_];
            sg[k] = fmaxf(sv, 0.0f) + log_(1.0f + exp_(-fabsf(sv)));
        }
        float ls = lc[0], ss = sg[0];
        #pragma unroll
        for (int k = 1; k < KM; ++k) {
            bool sel = (k == comp);
            ls = sel ? lc[k] : ls;
            ss = sel ? sg[k] : ss;
        }
        float invss = rcpf_(ss);
        float a  = (0.1f - ls) * invss;
        float bb = (3.9f - ls) * invss;
        v2f Fab = ndtr2_f((v2f){a, bb});
        float p  = Fab.x + u_trunc[(size_t)b*NL + ll_] * (Fab.y - Fab.x);
        p = fminf(fmaxf(p, 0.0f), 1.0f);
        float z = ndtri_f(p);
        if (p <= 0.0f) z = -INFINITY;
        if (p >= 1.0f) z =  INFINITY;
        float smp = fminf(fmaxf(fmaf(ss, z, ls), 0.1f), 3.9f);

        #pragma unroll
        for (int k = 0; k < KM; ++k) {
            float invs = rcpf_(sg[k]);
            float zc = (smp - lc[k]) * invs;
            float a_ = (-lc[k]) * invs;
            float b_ = (4.0f - lc[k]) * invs;
            v2f Fz = ndtr2_f((v2f){b_, a_});
            float Z  = Fz.x - Fz.y;                // >= ~0.29
            float v  = fmaf(-0.5f, zc*zc, -0.5f*LOG2PI_F) - log_(sg[k] * Z);
            cacc[k] += active ? v : 0.0f;
        }
        const float SQM = 7.9267442e-04f;     // sqrt(MU/2)
        const float HLN10 = 1.1512925f;       // 0.5*ln(10)
        float em  = exp_(-HLN10 * smp);       // 10^(-smp/2)
        float emi = SQM * rcpf_(em);          // SQM*10^(+smp/2)
        if (r == 0) {
            float th = x[(size_t)b*XROW + i];
            lds_pr[bl][1+i] = 2.0f * th * SQM * em;
            lds_pr[bl][5+i] = emi;
        } else if (active) {                  // lane 0: layer 4
            lds_pr[bl][0] = emi;
        }
    }
    #pragma unroll
    for (int k = 0; k < KM; ++k) {
        cacc[k] += __shfl_xor(cacc[k], 1, 4);
        cacc[k] += __shfl_xor(cacc[k], 2, 4);
    }
    {
        float mx = -INFINITY;
        float av[KM];
        #pragma unroll
        for (int k = 0; k < KM; ++k) { av[k] = log_(pro[k]) + cacc[k]; mx = fmaxf(mx, av[k]); }
        float se = 0.0f;
        #pragma unroll
        for (int k = 0; k < KM; ++k) se += exp_(av[k] - mx);
        if (i == 0) lqv = mx + log_(se);
    }
    __syncthreads();

    // --- forward phase: 3 quad-evals, 2 independent pair-states each ---
    float pr[9];
    #pragma unroll
    for (int q = 0; q < 9; ++q) pr[q] = lds_pr[bl][q];
    const float* oAr = x + (size_t)b * XROW + NL;
    const float* oPr = oAr + MF;

    float ex0 = fmaf((float)i, 0.10204082f, -2.0f);
    v2f c5 = {5.1026102f - ex0, 5.1026102f - ex0 - 2.5510204f};
    v2f sw = {2.5066283f * exp_(1.1512925f * ex0),
              2.5066283f * exp_(1.1512925f * (ex0 + 2.5510204f))};
    const float SWP[6] = {1.0f, 1.5998587f, 2.5595479f,
                          4.0949150f, 6.5512855f, 10.4811311f};   // 10^(2*0.10204082*k/... )
    const float C5P[6] = {0.0f, 0.40816327f, 0.81632653f,
                          1.2244898f, 1.6326531f, 2.0408163f};
    float ll = 0.0f;
    #pragma unroll
    for (int q = 0; q < 3; ++q) {
        int m  = (int)i + 4*q;          // pairs (m, m+25)
        int m2 = m + 12;                // pairs (m+12, m+37)
        v2f oAa = {oAr[m],  oAr[m+25]};
        v2f oPa = {oPr[m],  oPr[m+25]};
        v2f oAb = {oAr[m2], oAr[m2+25]};
        v2f oPb = {oPr[m2], oPr[m2+25]};
        ll += fwd_eval2x2(c5 - C5P[q],   sw * SWP[q],   oAa, oPa,
                          c5 - C5P[q+3], sw * SWP[q+3], oAb, oPb, pr);
    }
    // uniform tail: wave 0 covers 64 batches x packed pair (24, 49)
    if (tid < 64) {
        unsigned bt = blockIdx.x * BPB + tid;
        float prt[9];
        #pragma unroll
        for (int q = 0; q < 9; ++q) prt[q] = lds_pr[tid][q];
        const float* xa = x + (size_t)bt * XROW + NL;
        float e24 = fmaf(24.0f, 0.10204082f, -2.0f);
        float e49 = fmaf(49.0f, 0.10204082f, -2.0f);
        v2f c5t = {5.1026102f - e24, 5.1026102f - e49};
        v2f swt = {2.5066283f * exp_(1.1512925f * e24),
                   2.5066283f * exp_(1.1512925f * e49)};
        v2f oAt = {xa[24], xa[49]};
        v2f oPt = {xa[MF + 24], xa[MF + 49]};
        ll += fwd_eval2(c5t, swt, oAt, oPt, prt);
    }

    #pragma unroll
    for (int off = 32; off > 0; off >>= 1) {
        ll  += __shfl_down(ll,  off, 64);
        lqv += __shfl_down(lqv, off, 64);
    }
    if ((tid & 63) == 0) {
        red0[tid >> 6] = ll;
        red1[tid >> 6] = lqv;
    }
    __syncthreads();
    if (tid == 0) {
        p_ll[blockIdx.x] = red0[0] + red0[1] + red0[2] + red0[3];
        p_lq[blockIdx.x] = red1[0] + red1[1] + red1[2] + red1[3];
    }
}

// ---------------- fallback (tiny ws): serial per-batch ----------------
__global__ void __launch_bounds__(256) k_mono(
    const float* __restrict__ x, const float* __restrict__ s,
    const float* __restrict__ u_cat, const float* __restrict__ u_trunc,
    float* __restrict__ p_ll, float* __restrict__ p_lq)
{
    int b = blockIdx.x * 256 + threadIdx.x;
    const float* srow = s + (size_t)b * SROW;
    float loc[KM][NL], sig[KM][NL], pro[KM];
    float sqsum = 0.0f;
    #pragma unroll
    for (int k = 0; k < KM; ++k) { float v = srow[k*11+10]; pro[k] = v*v; sqsum += pro[k]; }
    float isq = rcpf_(sqsum);
    #pragma unroll
    for (int k = 0; k < KM; ++k) pro[k] *= isq;
    #pragma unroll
    for (int k = 0; k < KM; ++k)
        #pragma unroll
        for (int i = 0; i < NL; ++i) {
            loc[k][i] = 4.0f * rcpf_(1.0f + exp_(-srow[k*11+i]));
            float v = srow[k*11+5+i];
            sig[k][i] = fmaxf(v, 0.0f) + log_(1.0f + exp_(-fabsf(v)));
        }
    float u = u_cat[b];
    float cum = 0.0f; int cnt = 0;
    #pragma unroll
    for (int k = 0; k < KM; ++k) { cum += pro[k]; if (u > cum) ++cnt; }
    int comp = cnt < KM-1 ? cnt : KM-1;
    float ls[NL], ss[NL];
    #pragma unroll
    for (int i = 0; i < NL; ++i) { ls[i] = loc[0][i]; ss[i] = sig[0][i]; }
    #pragma unroll
    for (int k = 1; k < KM; ++k) {
        bool sel = (k == comp);
        #pragma unroll
        for (int i = 0; i < NL; ++i) {
            ls[i] = sel ? loc[k][i] : ls[i];
            ss[i] = sel ? sig[k][i] : ss[i];
        }
    }
    float smp[NL];
    #pragma unroll
    for (int i = 0; i < NL; ++i) {
        float invss = rcpf_(ss[i]);
        float a  = (0.1f - ls[i]) * invss;
        float bb = (3.9f - ls[i]) * invss;
        float Fa = ndtr_f(a), Fb = ndtr_f(bb);
        float p  = Fa + u_trunc[(size_t)b*NL + i] * (Fb - Fa);
        p = fminf(fmaxf(p, 0.0f), 1.0f);
        float z  = ndtri_f(p);
        if (p <= 0.0f) z = -INFINITY;
        if (p >= 1.0f) z =  INFINITY;
        smp[i] = fminf(fmaxf(fmaf(ss[i], z, ls[i]), 0.1f), 3.9f);
    }
    float vals[KM]; float mx = -INFINITY;
    #pragma unroll
    for (int k = 0; k < KM; ++k) {
        float av = log_(pro[k]);
        #pragma unroll
        for (int i = 0; i < NL; ++i) {
            float l = loc[k][i], sgv = sig[k][i];
            float invs = rcpf_(sgv);
            float zc = (smp[i] - l) * invs;
            float a_ = (-l) * invs;
            float b_ = (4.0f - l) * invs;
            float Z  = ndtr_f(b_) - ndtr_f(a_);
            av += fmaf(-0.5f, zc*zc, -0.5f*LOG2PI_F) - log_(sgv * Z);
        }
        vals[k] = av; mx = fmaxf(mx, av);
    }
    float se = 0.0f;
    #pragma unroll
    for (int k = 0; k < KM; ++k) se += exp_(vals[k] - mx);
    float lq = mx + log_(se);
    const float SQM = 7.9267442e-04f;
    const float HLN10 = 1.1512925f;
    float pr[9];
    pr[0] = SQM * exp_(HLN10 * smp[NL-1]);
    #pragma unroll
    for (int j = 0; j < NL-1; ++j) {
        float em = exp_(-HLN10 * smp[j]);
        float th = x[(size_t)b*XROW + j];
        pr[1+j] = 2.0f * th * SQM * em;
        pr[5+j] = SQM * rcpf_(em);
    }
    const float* xrow = x + (size_t)b * XROW;
    float ll = 0.0f;
    for (int m = 0; m < MF; ++m) {
        float ex = fmaf((float)m, 0.10204082f, -2.0f);
        float sw = 2.5066283f * exp_(1.1512925f * ex);
        ll += fwd_eval(5.1026102f - ex, sw, xrow[NL + m], xrow[NL + MF + m], pr);
    }

    __shared__ float red0[4], red1[4];
    #pragma unroll
    for (int off = 32; off > 0; off >>= 1) {
        ll += __shfl_down(ll, off, 64);
        lq += __shfl_down(lq, off, 64);
    }
    if ((threadIdx.x & 63) == 0) { red0[threadIdx.x>>6] = ll; red1[threadIdx.x>>6] = lq; }
    __syncthreads();
    if (threadIdx.x == 0) {
        p_ll[blockIdx.x] = red0[0]+red0[1]+red0[2]+red0[3];
        p_lq[blockIdx.x] = red1[0]+red1[1]+red1[2]+red1[3];
    }
}

// ---------------- final reduction ----------------
__global__ void __launch_bounds__(256) k_fin(
    const float* __restrict__ p_ll, const float* __restrict__ p_lq, int n,
    float* __restrict__ out)
{
    int tid = threadIdx.x;
    double a1 = 0.0, a0 = 0.0;
    for (int j = tid; j < n; j += 256) {
        a1 += (double)p_ll[j];
        a0 += (double)p_lq[j];
    }
    #pragma unroll
    for (int off = 32; off > 0; off >>= 1) {
        a0 += __shfl_down(a0, off, 64);
        a1 += __shfl_down(a1, off, 64);
    }
    __shared__ double r0[4], r1[4];
    if ((tid & 63) == 0) { r0[tid >> 6] = a0; r1[tid >> 6] = a1; }
    __syncthreads();
    if (tid == 0) {
        double A0 = r0[0]+r0[1]+r0[2]+r0[3];
        double A1 = r1[0]+r1[1]+r1[2]+r1[3];
        double term_lik = -A1 / ((double)BATCH_ * (double)(2*MF));
        double term_q   =  A0 / (double)BATCH_;
        out[0] = (float)(term_lik + term_q + 1.3862943611198906); // + log 4
    }
}

extern "C" void kernel_launch(void* const* d_in, const int* in_sizes, int n_in,
                              void* d_out, int out_size, void* d_ws, size_t ws_size,
                              hipStream_t stream)
{
    (void)in_sizes; (void)n_in; (void)out_size;
    const float* x       = (const float*)d_in[0];
    const float* s       = (const float*)d_in[1];
    const float* u_cat   = (const float*)d_in[2];
    const float* u_trunc = (const float*)d_in[3];
    float* out = (float*)d_out;

    float* p_ll = (float*)d_ws;             // [NB_FUSED]
    float* p_lq = p_ll + NB_FUSED;          // [NB_FUSED]
    size_t needed = (size_t)2 * NB_FUSED * sizeof(float);   // 16 KB

    if (ws_size >= needed) {
        k_bnn<<<NB_FUSED, 256, 0, stream>>>(x, s, u_cat, u_trunc, p_ll, p_lq);
        k_fin<<<1, 256, 0, stream>>>(p_ll, p_lq, NB_FUSED, out);
    } else {
        k_mono<<<NB_MONO, 256, 0, stream>>>(x, s, u_cat, u_trunc, p_ll, p_lq);
        k_fin<<<1, 256, 0, stream>>>(p_ll, p_lq, NB_MONO, out);
    }
}

// Round 6
// 132.334 us; speedup vs baseline: 1.0392x; 1.0392x over previous
//
#include <hip/hip_runtime.h>
#include <math.h>

#define NL 5
#define KM 5
#define MF 50
#define BATCH_ 131072
#define XROW (NL + 2*MF)      /* 105 */
#define SROW (KM*(2*NL+1))    /* 55  */
#define LOG2PI_F 1.8378770664093453f

#define BPB 64                    /* batches per block, 4 lanes per batch */
#define NB_FUSED (BATCH_/BPB)     /* 2048 */

typedef float v2f __attribute__((ext_vector_type(2)));

__device__ __forceinline__ float rcpf_(float x)  { return __builtin_amdgcn_rcpf(x); }
__device__ __forceinline__ float sqrtf_(float x) { return __builtin_amdgcn_sqrtf(x); }
__device__ __forceinline__ float exp_(float x)   { return __expf(x); }
__device__ __forceinline__ float log_(float x)   { return __logf(x); }

// packed 2-wide ndtr via A&S 7.1.26 erf (|eps| <= 1.5e-7)
__device__ __forceinline__ v2f ndtr2_f(v2f x) {
    v2f z = {fabsf(x.x), fabsf(x.y)};
    z = z * 0.70710678f;
    v2f td = 0.3275911f * z + 1.0f;
    v2f t  = {rcpf_(td.x), rcpf_(td.y)};
    v2f poly = t*(0.254829592f + t*(-0.284496736f + t*(1.421413741f +
               t*(-1.453152027f + t*1.061405429f))));
    v2f zz = z * z;
    v2f e  = {exp_(-zz.x), exp_(-zz.y)};
    v2f h  = 0.5f * poly * e;
    v2f r;
    r.x = x.x >= 0.0f ? 1.0f - h.x : h.x;
    r.y = x.y >= 0.0f ? 1.0f - h.y : h.y;
    return r;
}

// ndtri via Giles' erfinv. Caller overrides exact endpoints.
__device__ __forceinline__ float ndtri_f(float p) {
    float x = fmaf(2.0f, p, -1.0f);
    float w = -log_((1.0f - x) * (1.0f + x));
    float wc = w - 2.5f;
    float pc =            2.81022636e-08f;
    pc = fmaf(pc, wc,     3.43273939e-07f);
    pc = fmaf(pc, wc,    -3.5233877e-06f);
    pc = fmaf(pc, wc,    -4.39150654e-06f);
    pc = fmaf(pc, wc,     0.00021858087f);
    pc = fmaf(pc, wc,    -0.00125372503f);
    pc = fmaf(pc, wc,    -0.00417768164f);
    pc = fmaf(pc, wc,     0.246640727f);
    pc = fmaf(pc, wc,     1.50140941f);
    float wt = sqrtf_(w) - 3.0f;
    float pt =           -0.000200214257f;
    pt = fmaf(pt, wt,     0.000100950558f);
    pt = fmaf(pt, wt,     0.00134934322f);
    pt = fmaf(pt, wt,    -0.00367342844f);
    pt = fmaf(pt, wt,     0.00573950773f);
    pt = fmaf(pt, wt,    -0.0076224613f);
    pt = fmaf(pt, wt,     0.00943887047f);
    pt = fmaf(pt, wt,     1.00167406f);
    pt = fmaf(pt, wt,     2.83297682f);
    float r = (w < 5.0f) ? pc : pt;
    return 1.41421356f * r * x;
}

// octant-reduced atan2, degree-11 odd minimax (~1e-6 rad)
__device__ __forceinline__ float atan2_f(float y, float x) {
    float ax = fabsf(x), ay = fabsf(y);
    float mx = fmaxf(ax, ay), mn = fminf(ax, ay);
    float a = mn * rcpf_(mx);
    float s = a * a;
    float r =            -0.01172120f;
    r = fmaf(r, s,        0.05265332f);
    r = fmaf(r, s,       -0.11643287f);
    r = fmaf(r, s,        0.19354346f);
    r = fmaf(r, s,       -0.33262347f);
    r = fmaf(r, s,        0.99997726f);
    r = r * a;
    r = (ay > ax)   ? (1.5707964f - r) : r;
    r = (x < 0.0f)  ? (3.1415927f - r) : r;
    return (y < 0.0f) ? -r : r;
}

// ---------- packed forward model: TWO INDEPENDENT FREQUENCIES per call ------
// Division-free Mobius recursion; zeta = wj*(1+i); zeta*d full complex mul.
__device__ __forceinline__ float fwd_eval2(v2f c5, v2f sw, v2f oA, v2f oP,
                                           const float pr[9])
{
    v2f z0 = sw * pr[0];
    v2f nR = z0, nC = z0;
    v2f dR = {1.0f, 1.0f}, dC = {0.0f, 0.0f};
    #pragma unroll
    for (int j = NL-2; j >= 0; --j) {
        v2f wj = sw * pr[5+j];
        v2f t  = sw * pr[1+j];
        v2f t2 = t * t, t3 = t2 * t;
        v2f ejR = (1.0f - t) + t3 * (0.33333334f - 0.16666667f * t);
        v2f ejC = t2 - 0.33333334f * t3 - t;
        v2f pRz = wj * (dR - dC);
        v2f pCz = wj * (dR + dC);
        v2f uR = pRz + nR, uC = pCz + nC;
        v2f vR = pRz - nR, vC = pCz - nC;
        v2f wR = ejR*vR - ejC*vC;
        v2f wC = ejR*vC + ejC*vR;
        v2f aR = uR - wR, aC = uC - wC;
        nR = wj * (aR - aC);
        nC = wj * (aR + aC);
        dR = uR + wR;
        dC = uC + wC;
    }
    v2f n2 = nR*nR + nC*nC;
    v2f d2 = dR*dR + dC*dC;
    v2f id2 = {rcpf_(d2.x), rcpf_(d2.y)};
    v2f absZ2 = n2 * id2;
    v2f mR = nR*dR + nC*dC;
    v2f mC = nC*dR - nR*dC;
    v2f aRes = {fmaf(0.43429448f, log_(absZ2.x), c5.x),
                fmaf(0.43429448f, log_(absZ2.y), c5.y)};
    v2f ph   = {atan2_f(mC.x, mR.x), atan2_f(mC.y, mR.y)};
    v2f prod = aRes * ph;
    v2f ap   = {fabsf(prod.x), fabsf(prod.y)};
    v2f invp = {rcpf_(ap.x), rcpf_(ap.y)};
    v2f aph  = {fabsf(ph.x),   fabsf(ph.y)};
    v2f aar  = {fabsf(aRes.x), fabsf(aRes.y)};
    v2f vA = (aRes - oA) * (33.333332f * aph * invp);
    v2f vP = (ph   - oP) * (33.333332f * aar * invp);
    v2f res = (v2f){5.1752387f - log_(ap.x), 5.1752387f - log_(ap.y)}
              - 0.5f*vA*vA - 0.5f*vP*vP;
    return res.x + res.y;
}

// ---------- 2x2: TWO independent pair-evals advanced in lockstep ----------
__device__ __forceinline__ float fwd_eval2x2(
    v2f c5a, v2f swa, v2f oAa, v2f oPa,
    v2f c5b, v2f swb, v2f oAb, v2f oPb,
    const float pr[9])
{
    v2f z0a = swa * pr[0];
    v2f z0b = swb * pr[0];
    v2f nRa = z0a, nCa = z0a, dRa = {1.0f,1.0f}, dCa = {0.0f,0.0f};
    v2f nRb = z0b, nCb = z0b, dRb = {1.0f,1.0f}, dCb = {0.0f,0.0f};
    #pragma unroll
    for (int j = NL-2; j >= 0; --j) {
        float p5 = pr[5+j], p1 = pr[1+j];
        v2f wja = swa * p5;            v2f wjb = swb * p5;
        v2f ta  = swa * p1;            v2f tb  = swb * p1;
        v2f t2a = ta * ta;             v2f t2b = tb * tb;
        v2f t3a = t2a * ta;            v2f t3b = t2b * tb;
        v2f ejRa = (1.0f - ta) + t3a * (0.33333334f - 0.16666667f * ta);
        v2f ejRb = (1.0f - tb) + t3b * (0.33333334f - 0.16666667f * tb);
        v2f ejCa = t2a - 0.33333334f * t3a - ta;
        v2f ejCb = t2b - 0.33333334f * t3b - tb;
        v2f pRa = wja * (dRa - dCa);   v2f pRb = wjb * (dRb - dCb);
        v2f pCa = wja * (dRa + dCa);   v2f pCb = wjb * (dRb + dCb);
        v2f uRa = pRa + nRa;           v2f uRb = pRb + nRb;
        v2f uCa = pCa + nCa;           v2f uCb = pCb + nCb;
        v2f vRa = pRa - nRa;           v2f vRb = pRb - nRb;
        v2f vCa = pCa - nCa;           v2f vCb = pCb - nCb;
        v2f wRa = ejRa*vRa - ejCa*vCa; v2f wRb = ejRb*vRb - ejCb*vCb;
        v2f wCa = ejRa*vCa + ejCa*vRa; v2f wCb = ejRb*vCb + ejCb*vRb;
        v2f aRa = uRa - wRa;           v2f aRb = uRb - wRb;
        v2f aCa = uCa - wCa;           v2f aCb = uCb - wCb;
        nRa = wja * (aRa - aCa);       nRb = wjb * (aRb - aCb);
        nCa = wja * (aRa + aCa);       nCb = wjb * (aRb + aCb);
        dRa = uRa + wRa;               dRb = uRb + wRb;
        dCa = uCa + wCa;               dCb = uCb + wCb;
    }
    v2f n2a = nRa*nRa + nCa*nCa;       v2f n2b = nRb*nRb + nCb*nCb;
    v2f d2a = dRa*dRa + dCa*dCa;       v2f d2b = dRb*dRb + dCb*dCb;
    v2f id2a = {rcpf_(d2a.x), rcpf_(d2a.y)};
    v2f id2b = {rcpf_(d2b.x), rcpf_(d2b.y)};
    v2f absZ2a = n2a * id2a;           v2f absZ2b = n2b * id2b;
    v2f mRa = nRa*dRa + nCa*dCa;       v2f mRb = nRb*dRb + nCb*dCb;
    v2f mCa = nCa*dRa - nRa*dCa;       v2f mCb = nCb*dRb - nRb*dCb;
    v2f aResa = {fmaf(0.43429448f, log_(absZ2a.x), c5a.x),
                 fmaf(0.43429448f, log_(absZ2a.y), c5a.y)};
    v2f aResb = {fmaf(0.43429448f, log_(absZ2b.x), c5b.x),
                 fmaf(0.43429448f, log_(absZ2b.y), c5b.y)};
    v2f pha = {atan2_f(mCa.x, mRa.x), atan2_f(mCa.y, mRa.y)};
    v2f phb = {atan2_f(mCb.x, mRb.x), atan2_f(mCb.y, mRb.y)};
    v2f proda = aResa * pha;           v2f prodb = aResb * phb;
    v2f apa = {fabsf(proda.x), fabsf(proda.y)};
    v2f apb = {fabsf(prodb.x), fabsf(prodb.y)};
    v2f invpa = {rcpf_(apa.x), rcpf_(apa.y)};
    v2f invpb = {rcpf_(apb.x), rcpf_(apb.y)};
    v2f apha = {fabsf(pha.x),   fabsf(pha.y)};
    v2f aphb = {fabsf(phb.x),   fabsf(phb.y)};
    v2f aara = {fabsf(aResa.x), fabsf(aResa.y)};
    v2f aarb = {fabsf(aResb.x), fabsf(aResb.y)};
    v2f vAa = (aResa - oAa) * (33.333332f * apha * invpa);
    v2f vAb = (aResb - oAb) * (33.333332f * aphb * invpb);
    v2f vPa = (pha   - oPa) * (33.333332f * aara * invpa);
    v2f vPb = (phb   - oPb) * (33.333332f * aarb * invpb);
    v2f resa = (v2f){5.1752387f - log_(apa.x), 5.1752387f - log_(apa.y)}
               - 0.5f*vAa*vAa - 0.5f*vPa*vPa;
    v2f resb = (v2f){5.1752387f - log_(apb.x), 5.1752387f - log_(apb.y)}
               - 0.5f*vAb*vAb - 0.5f*vPb*vPb;
    return (resa.x + resa.y) + (resb.x + resb.y);
}

// ---------------- fused kernel (prep + packed fwd + direct atomic out) ------
// prep: all 256 threads, 4 lanes/batch (2 layer-reps per lane), 64 batches
// fwd : lane i handles pairs (i+4k, i+4k+25), k<6, as 3 quad-evals {k,k+3};
//       uniform tail pair (24,49) on wave 0.
// out : one atomicAdd per block of the block's final-scalar contribution
//       (out[] is zeroed by the harness before each launch; block 0 adds log4).
__global__ void __launch_bounds__(256, 4) k_bnn(
    const float* __restrict__ x, const float* __restrict__ s,
    const float* __restrict__ u_cat, const float* __restrict__ u_trunc,
    float* __restrict__ out)
{
    __shared__ float lds_pr[BPB][12];
    __shared__ float red0[4], red1[4];

    unsigned tid = threadIdx.x;
    unsigned bl = tid >> 2;               // 0..63
    unsigned i  = tid & 3;
    unsigned b  = blockIdx.x * BPB + bl;
    const float* srow = s + (size_t)b * SROW;
    float lqv = 0.0f;

    // --- batch-common (duplicated 4x per batch) ---
    float pro[KM];
    float sqsum = 0.0f;
    #pragma unroll
    for (int k = 0; k < KM; ++k) {
        float v = srow[k*11 + 10];
        pro[k] = v * v;
        sqsum += pro[k];
    }
    float isq = rcpf_(sqsum);
    #pragma unroll
    for (int k = 0; k < KM; ++k) pro[k] *= isq;
    float u = u_cat[b];
    float cum = 0.0f; int cnt = 0;
    #pragma unroll
    for (int k = 0; k < KM; ++k) { cum += pro[k]; if (u > cum) ++cnt; }
    int comp = cnt < KM-1 ? cnt : KM-1;

    // --- per-layer cells: rep 0 -> layer i, rep 1 -> layer i+4 (lane 0) ---
    float cacc[KM];
    #pragma unroll
    for (int k = 0; k < KM; ++k) cacc[k] = 0.0f;

    #pragma unroll
    for (int r = 0; r < 2; ++r) {
        unsigned layer = i + 4u*r;
        bool active = (layer < NL);
        unsigned ll_ = active ? layer : i;
        float lc[KM], sg[KM];
        #pragma unroll
        for (int k = 0; k < KM; ++k) {
            lc[k] = 4.0f * rcpf_(1.0f + exp_(-srow[k*11 + ll_]));
            float sv = srow[k*11 + 5 + ll_];
            sg[k] = fmaxf(sv, 0.0f) + log_(1.0f + exp_(-fabsf(sv)));
        }
        float ls = lc[0], ss = sg[0];
        #pragma unroll
        for (int k = 1; k < KM; ++k) {
            bool sel = (k == comp);
            ls = sel ? lc[k] : ls;
            ss = sel ? sg[k] : ss;
        }
        float invss = rcpf_(ss);
        float a  = (0.1f - ls) * invss;
        float bb = (3.9f - ls) * invss;
        v2f Fab = ndtr2_f((v2f){a, bb});
        float p  = Fab.x + u_trunc[(size_t)b*NL + ll_] * (Fab.y - Fab.x);
        p = fminf(fmaxf(p, 0.0f), 1.0f);
        float z = ndtri_f(p);
        if (p <= 0.0f) z = -INFINITY;
        if (p >= 1.0f) z =  INFINITY;
        float smp = fminf(fmaxf(fmaf(ss, z, ls), 0.1f), 3.9f);

        #pragma unroll
        for (int k = 0; k < KM; ++k) {
            float invs = rcpf_(sg[k]);
            float zc = (smp - lc[k]) * invs;
            float a_ = (-lc[k]) * invs;
            float b_ = (4.0f - lc[k]) * invs;
            v2f Fz = ndtr2_f((v2f){b_, a_});
            float Z  = Fz.x - Fz.y;                // >= ~0.29
            float v  = fmaf(-0.5f, zc*zc, -0.5f*LOG2PI_F) - log_(sg[k] * Z);
            cacc[k] += active ? v : 0.0f;
        }
        const float SQM = 7.9267442e-04f;     // sqrt(MU/2)
        const float HLN10 = 1.1512925f;       // 0.5*ln(10)
        float em  = exp_(-HLN10 * smp);       // 10^(-smp/2)
        float emi = SQM * rcpf_(em);          // SQM*10^(+smp/2)
        if (r == 0) {
            float th = x[(size_t)b*XROW + i];
            lds_pr[bl][1+i] = 2.0f * th * SQM * em;
            lds_pr[bl][5+i] = emi;
        } else if (active) {                  // lane 0: layer 4
            lds_pr[bl][0] = emi;
        }
    }
    #pragma unroll
    for (int k = 0; k < KM; ++k) {
        cacc[k] += __shfl_xor(cacc[k], 1, 4);
        cacc[k] += __shfl_xor(cacc[k], 2, 4);
    }
    {
        float mx = -INFINITY;
        float av[KM];
        #pragma unroll
        for (int k = 0; k < KM; ++k) { av[k] = log_(pro[k]) + cacc[k]; mx = fmaxf(mx, av[k]); }
        float se = 0.0f;
        #pragma unroll
        for (int k = 0; k < KM; ++k) se += exp_(av[k] - mx);
        if (i == 0) lqv = mx + log_(se);
    }
    __syncthreads();

    // --- forward phase: 3 quad-evals, 2 independent pair-states each ---
    float pr[9];
    #pragma unroll
    for (int q = 0; q < 9; ++q) pr[q] = lds_pr[bl][q];
    const float* oAr = x + (size_t)b * XROW + NL;
    const float* oPr = oAr + MF;

    float ex0 = fmaf((float)i, 0.10204082f, -2.0f);
    v2f c5 = {5.1026102f - ex0, 5.1026102f - ex0 - 2.5510204f};
    v2f sw = {2.5066283f * exp_(1.1512925f * ex0),
              2.5066283f * exp_(1.1512925f * (ex0 + 2.5510204f))};
    const float SWP[6] = {1.0f, 1.5998587f, 2.5595479f,
                          4.0949150f, 6.5512855f, 10.4811311f};
    const float C5P[6] = {0.0f, 0.40816327f, 0.81632653f,
                          1.2244898f, 1.6326531f, 2.0408163f};
    float ll = 0.0f;
    #pragma unroll
    for (int q = 0; q < 3; ++q) {
        int m  = (int)i + 4*q;          // pairs (m, m+25)
        int m2 = m + 12;                // pairs (m+12, m+37)
        v2f oAa = {oAr[m],  oAr[m+25]};
        v2f oPa = {oPr[m],  oPr[m+25]};
        v2f oAb = {oAr[m2], oAr[m2+25]};
        v2f oPb = {oPr[m2], oPr[m2+25]};
        ll += fwd_eval2x2(c5 - C5P[q],   sw * SWP[q],   oAa, oPa,
                          c5 - C5P[q+3], sw * SWP[q+3], oAb, oPb, pr);
    }
    // uniform tail: wave 0 covers 64 batches x packed pair (24, 49)
    if (tid < 64) {
        unsigned bt = blockIdx.x * BPB + tid;
        float prt[9];
        #pragma unroll
        for (int q = 0; q < 9; ++q) prt[q] = lds_pr[tid][q];
        const float* xa = x + (size_t)bt * XROW + NL;
        float e24 = fmaf(24.0f, 0.10204082f, -2.0f);
        float e49 = fmaf(49.0f, 0.10204082f, -2.0f);
        v2f c5t = {5.1026102f - e24, 5.1026102f - e49};
        v2f swt = {2.5066283f * exp_(1.1512925f * e24),
                   2.5066283f * exp_(1.1512925f * e49)};
        v2f oAt = {xa[24], xa[49]};
        v2f oPt = {xa[MF + 24], xa[MF + 49]};
        ll += fwd_eval2(c5t, swt, oAt, oPt, prt);
    }

    #pragma unroll
    for (int off = 32; off > 0; off >>= 1) {
        ll  += __shfl_down(ll,  off, 64);
        lqv += __shfl_down(lqv, off, 64);
    }
    if ((tid & 63) == 0) {
        red0[tid >> 6] = ll;
        red1[tid >> 6] = lqv;
    }
    __syncthreads();
    if (tid == 0) {
        float llb = red0[0] + red0[1] + red0[2] + red0[3];
        float lqb = red1[0] + red1[1] + red1[2] + red1[3];
        // term_lik contribution: -llb / (BATCH*2*MF) = -llb/13107200
        // term_q   contribution: +lqb / BATCH       = +lqb/131072 (2^-17 exact)
        float val = fmaf(llb, -7.62939453125e-8f, lqb * 7.62939453125e-6f);
        if (blockIdx.x == 0) val += 1.3862944f;   // + log 4
        atomicAdd(out, val);
    }
}

extern "C" void kernel_launch(void* const* d_in, const int* in_sizes, int n_in,
                              void* d_out, int out_size, void* d_ws, size_t ws_size,
                              hipStream_t stream)
{
    (void)in_sizes; (void)n_in; (void)out_size; (void)d_ws; (void)ws_size;
    const float* x       = (const float*)d_in[0];
    const float* s       = (const float*)d_in[1];
    const float* u_cat   = (const float*)d_in[2];
    const float* u_trunc = (const float*)d_in[3];
    float* out = (float*)d_out;

    k_bnn<<<NB_FUSED, 256, 0, stream>>>(x, s, u_cat, u_trunc, out);
}

// Round 8
// 131.453 us; speedup vs baseline: 1.0462x; 1.0067x over previous
//
#include <hip/hip_runtime.h>
#include <math.h>

#define NL 5
#define KM 5
#define MF 50
#define BATCH_ 131072
#define XROW (NL + 2*MF)      /* 105 */
#define SROW (KM*(2*NL+1))    /* 55  */
#define LOG2PI_F 1.8378770664093453f

#define BPB 64                    /* batches per block, 4 lanes per batch */
#define NB_FUSED (BATCH_/BPB)     /* 2048 */
#define NCELL (BPB*NL)            /* 320 layer-cells per block */

typedef float v2f __attribute__((ext_vector_type(2)));

__device__ __forceinline__ float rcpf_(float x)  { return __builtin_amdgcn_rcpf(x); }
__device__ __forceinline__ float sqrtf_(float x) { return __builtin_amdgcn_sqrtf(x); }
__device__ __forceinline__ float exp_(float x)   { return __expf(x); }
__device__ __forceinline__ float log_(float x)   { return __logf(x); }

// packed 2-wide ndtr via A&S 7.1.26 erf (|eps| <= 1.5e-7)
__device__ __forceinline__ v2f ndtr2_f(v2f x) {
    v2f z = {fabsf(x.x), fabsf(x.y)};
    z = z * 0.70710678f;
    v2f td = 0.3275911f * z + 1.0f;
    v2f t  = {rcpf_(td.x), rcpf_(td.y)};
    v2f poly = t*(0.254829592f + t*(-0.284496736f + t*(1.421413741f +
               t*(-1.453152027f + t*1.061405429f))));
    v2f zz = z * z;
    v2f e  = {exp_(-zz.x), exp_(-zz.y)};
    v2f h  = 0.5f * poly * e;
    v2f r;
    r.x = x.x >= 0.0f ? 1.0f - h.x : h.x;
    r.y = x.y >= 0.0f ? 1.0f - h.y : h.y;
    return r;
}

// ndtri via Giles' erfinv. Caller overrides exact endpoints.
__device__ __forceinline__ float ndtri_f(float p) {
    float x = fmaf(2.0f, p, -1.0f);
    float w = -log_((1.0f - x) * (1.0f + x));
    float wc = w - 2.5f;
    float pc =            2.81022636e-08f;
    pc = fmaf(pc, wc,     3.43273939e-07f);
    pc = fmaf(pc, wc,    -3.5233877e-06f);
    pc = fmaf(pc, wc,    -4.39150654e-06f);
    pc = fmaf(pc, wc,     0.00021858087f);
    pc = fmaf(pc, wc,    -0.00125372503f);
    pc = fmaf(pc, wc,    -0.00417768164f);
    pc = fmaf(pc, wc,     0.246640727f);
    pc = fmaf(pc, wc,     1.50140941f);
    float wt = sqrtf_(w) - 3.0f;
    float pt =           -0.000200214257f;
    pt = fmaf(pt, wt,     0.000100950558f);
    pt = fmaf(pt, wt,     0.00134934322f);
    pt = fmaf(pt, wt,    -0.00367342844f);
    pt = fmaf(pt, wt,     0.00573950773f);
    pt = fmaf(pt, wt,    -0.0076224613f);
    pt = fmaf(pt, wt,     0.00943887047f);
    pt = fmaf(pt, wt,     1.00167406f);
    pt = fmaf(pt, wt,     2.83297682f);
    float r = (w < 5.0f) ? pc : pt;
    return 1.41421356f * r * x;
}

// octant-reduced atan2, degree-11 odd minimax (~1e-6 rad)
__device__ __forceinline__ float atan2_f(float y, float x) {
    float ax = fabsf(x), ay = fabsf(y);
    float mx = fmaxf(ax, ay), mn = fminf(ax, ay);
    float a = mn * rcpf_(mx);
    float s = a * a;
    float r =            -0.01172120f;
    r = fmaf(r, s,        0.05265332f);
    r = fmaf(r, s,       -0.11643287f);
    r = fmaf(r, s,        0.19354346f);
    r = fmaf(r, s,       -0.33262347f);
    r = fmaf(r, s,        0.99997726f);
    r = r * a;
    r = (ay > ax)   ? (1.5707964f - r) : r;
    r = (x < 0.0f)  ? (3.1415927f - r) : r;
    return (y < 0.0f) ? -r : r;
}

// ---------- packed forward model: TWO INDEPENDENT FREQUENCIES per call ------
// Division-free Mobius recursion; zeta = wj*(1+i); zeta*d full complex mul.
__device__ __forceinline__ float fwd_eval2(v2f c5, v2f sw, v2f oA, v2f oP,
                                           const float pr[9])
{
    v2f z0 = sw * pr[0];
    v2f nR = z0, nC = z0;
    v2f dR = {1.0f, 1.0f}, dC = {0.0f, 0.0f};
    #pragma unroll
    for (int j = NL-2; j >= 0; --j) {
        v2f wj = sw * pr[5+j];
        v2f t  = sw * pr[1+j];
        v2f t2 = t * t, t3 = t2 * t;
        v2f ejR = (1.0f - t) + t3 * (0.33333334f - 0.16666667f * t);
        v2f ejC = t2 - 0.33333334f * t3 - t;
        v2f pRz = wj * (dR - dC);
        v2f pCz = wj * (dR + dC);
        v2f uR = pRz + nR, uC = pCz + nC;
        v2f vR = pRz - nR, vC = pCz - nC;
        v2f wR = ejR*vR - ejC*vC;
        v2f wC = ejR*vC + ejC*vR;
        v2f aR = uR - wR, aC = uC - wC;
        nR = wj * (aR - aC);
        nC = wj * (aR + aC);
        dR = uR + wR;
        dC = uC + wC;
    }
    v2f n2 = nR*nR + nC*nC;
    v2f d2 = dR*dR + dC*dC;
    v2f id2 = {rcpf_(d2.x), rcpf_(d2.y)};
    v2f absZ2 = n2 * id2;
    v2f mR = nR*dR + nC*dC;
    v2f mC = nC*dR - nR*dC;
    v2f aRes = {fmaf(0.43429448f, log_(absZ2.x), c5.x),
                fmaf(0.43429448f, log_(absZ2.y), c5.y)};
    v2f ph   = {atan2_f(mC.x, mR.x), atan2_f(mC.y, mR.y)};
    v2f prod = aRes * ph;
    v2f ap   = {fabsf(prod.x), fabsf(prod.y)};
    v2f invp = {rcpf_(ap.x), rcpf_(ap.y)};
    v2f aph  = {fabsf(ph.x),   fabsf(ph.y)};
    v2f aar  = {fabsf(aRes.x), fabsf(aRes.y)};
    v2f vA = (aRes - oA) * (33.333332f * aph * invp);
    v2f vP = (ph   - oP) * (33.333332f * aar * invp);
    v2f res = (v2f){5.1752387f - log_(ap.x), 5.1752387f - log_(ap.y)}
              - 0.5f*vA*vA - 0.5f*vP*vP;
    return res.x + res.y;
}

// ---------- 2x2: TWO independent pair-evals advanced in lockstep ----------
__device__ __forceinline__ float fwd_eval2x2(
    v2f c5a, v2f swa, v2f oAa, v2f oPa,
    v2f c5b, v2f swb, v2f oAb, v2f oPb,
    const float pr[9])
{
    v2f z0a = swa * pr[0];
    v2f z0b = swb * pr[0];
    v2f nRa = z0a, nCa = z0a, dRa = {1.0f,1.0f}, dCa = {0.0f,0.0f};
    v2f nRb = z0b, nCb = z0b, dRb = {1.0f,1.0f}, dCb = {0.0f,0.0f};
    #pragma unroll
    for (int j = NL-2; j >= 0; --j) {
        float p5 = pr[5+j], p1 = pr[1+j];
        v2f wja = swa * p5;            v2f wjb = swb * p5;
        v2f ta  = swa * p1;            v2f tb  = swb * p1;
        v2f t2a = ta * ta;             v2f t2b = tb * tb;
        v2f t3a = t2a * ta;            v2f t3b = t2b * tb;
        v2f ejRa = (1.0f - ta) + t3a * (0.33333334f - 0.16666667f * ta);
        v2f ejRb = (1.0f - tb) + t3b * (0.33333334f - 0.16666667f * tb);
        v2f ejCa = t2a - 0.33333334f * t3a - ta;
        v2f ejCb = t2b - 0.33333334f * t3b - tb;
        v2f pRa = wja * (dRa - dCa);   v2f pRb = wjb * (dRb - dCb);
        v2f pCa = wja * (dRa + dCa);   v2f pCb = wjb * (dRb + dCb);
        v2f uRa = pRa + nRa;           v2f uRb = pRb + nRb;
        v2f uCa = pCa + nCa;           v2f uCb = pCb + nCb;
        v2f vRa = pRa - nRa;           v2f vRb = pRb - nRb;
        v2f vCa = pCa - nCa;           v2f vCb = pCb - nCb;
        v2f wRa = ejRa*vRa - ejCa*vCa; v2f wRb = ejRb*vRb - ejCb*vCb;
        v2f wCa = ejRa*vCa + ejCa*vRa; v2f wCb = ejRb*vCb + ejCb*vRb;
        v2f aRa = uRa - wRa;           v2f aRb = uRb - wRb;
        v2f aCa = uCa - wCa;           v2f aCb = uCb - wCb;
        nRa = wja * (aRa - aCa);       nRb = wjb * (aRb - aCb);
        nCa = wja * (aRa + aCa);       nCb = wjb * (aRb + aCb);
        dRa = uRa + wRa;               dRb = uRb + wRb;
        dCa = uCa + wCa;               dCb = uCb + wCb;
    }
    v2f n2a = nRa*nRa + nCa*nCa;       v2f n2b = nRb*nRb + nCb*nCb;
    v2f d2a = dRa*dRa + dCa*dCa;       v2f d2b = dRb*dRb + dCb*dCb;
    v2f id2a = {rcpf_(d2a.x), rcpf_(d2a.y)};
    v2f id2b = {rcpf_(d2b.x), rcpf_(d2b.y)};
    v2f absZ2a = n2a * id2a;           v2f absZ2b = n2b * id2b;
    v2f mRa = nRa*dRa + nCa*dCa;       v2f mRb = nRb*dRb + nCb*dCb;
    v2f mCa = nCa*dRa - nRa*dCa;       v2f mCb = nCb*dRb - nRb*dCb;
    v2f aResa = {fmaf(0.43429448f, log_(absZ2a.x), c5a.x),
                 fmaf(0.43429448f, log_(absZ2a.y), c5a.y)};
    v2f aResb = {fmaf(0.43429448f, log_(absZ2b.x), c5b.x),
                 fmaf(0.43429448f, log_(absZ2b.y), c5b.y)};
    v2f pha = {atan2_f(mCa.x, mRa.x), atan2_f(mCa.y, mRa.y)};
    v2f phb = {atan2_f(mCb.x, mRb.x), atan2_f(mCb.y, mRb.y)};
    v2f proda = aResa * pha;           v2f prodb = aResb * phb;
    v2f apa = {fabsf(proda.x), fabsf(proda.y)};
    v2f apb = {fabsf(prodb.x), fabsf(prodb.y)};
    v2f invpa = {rcpf_(apa.x), rcpf_(apa.y)};
    v2f invpb = {rcpf_(apb.x), rcpf_(apb.y)};
    v2f apha = {fabsf(pha.x),   fabsf(pha.y)};
    v2f aphb = {fabsf(phb.x),   fabsf(phb.y)};
    v2f aara = {fabsf(aResa.x), fabsf(aResa.y)};
    v2f aarb = {fabsf(aResb.x), fabsf(aResb.y)};
    v2f vAa = (aResa - oAa) * (33.333332f * apha * invpa);
    v2f vAb = (aResb - oAb) * (33.333332f * aphb * invpb);
    v2f vPa = (pha   - oPa) * (33.333332f * aara * invpa);
    v2f vPb = (phb   - oPb) * (33.333332f * aarb * invpb);
    v2f resa = (v2f){5.1752387f - log_(apa.x), 5.1752387f - log_(apa.y)}
               - 0.5f*vAa*vAa - 0.5f*vPa*vPa;
    v2f resb = (v2f){5.1752387f - log_(apb.x), 5.1752387f - log_(apb.y)}
               - 0.5f*vAb*vAb - 0.5f*vPb*vPb;
    return (resa.x + resa.y) + (resb.x + resb.y);
}

// ---------- one layer-cell of prep work (exact 320-cell mapping) ----------
// cell c -> batch c/5, layer c%5. Writes: cc[batch][layer][k] (5 floats),
// and pr entries (layer<4: pr[1+l], pr[5+l]; layer 4: pr[0]).
__device__ __forceinline__ void process_cell(
    unsigned c, unsigned block_b0,
    const float* __restrict__ x, const float* __restrict__ s,
    const float* __restrict__ u_cat, const float* __restrict__ u_trunc,
    float lds_cc[BPB][NL][KM], float lds_pr[BPB][12])
{
    unsigned cb = c / NL;                 // batch-in-block 0..63
    unsigned cl = c - cb * NL;            // layer 0..4
    unsigned b  = block_b0 + cb;
    const float* srow = s + (size_t)b * SROW;

    // batch-common component selection (identical formula to prior rounds)
    float pro[KM];
    float sqsum = 0.0f;
    #pragma unroll
    for (int k = 0; k < KM; ++k) {
        float v = srow[k*11 + 10];
        pro[k] = v * v;
        sqsum += pro[k];
    }
    float isq = rcpf_(sqsum);
    #pragma unroll
    for (int k = 0; k < KM; ++k) pro[k] *= isq;
    float u = u_cat[b];
    float cum = 0.0f; int cnt = 0;
    #pragma unroll
    for (int k = 0; k < KM; ++k) { cum += pro[k]; if (u > cum) ++cnt; }
    int comp = cnt < KM-1 ? cnt : KM-1;

    // this layer's loc/sig for all components
    float lc[KM], sg[KM];
    #pragma unroll
    for (int k = 0; k < KM; ++k) {
        lc[k] = 4.0f * rcpf_(1.0f + exp_(-srow[k*11 + cl]));
        float sv = srow[k*11 + 5 + cl];
        sg[k] = fmaxf(sv, 0.0f) + log_(1.0f + exp_(-fabsf(sv)));
    }
    float ls = lc[0], ss = sg[0];
    #pragma unroll
    for (int k = 1; k < KM; ++k) {
        bool sel = (k == comp);
        ls = sel ? lc[k] : ls;
        ss = sel ? sg[k] : ss;
    }
    float invss = rcpf_(ss);
    float a  = (0.1f - ls) * invss;
    float bb = (3.9f - ls) * invss;
    v2f Fab = ndtr2_f((v2f){a, bb});
    float p  = Fab.x + u_trunc[(size_t)b*NL + cl] * (Fab.y - Fab.x);
    p = fminf(fmaxf(p, 0.0f), 1.0f);
    float z = ndtri_f(p);
    if (p <= 0.0f) z = -INFINITY;
    if (p >= 1.0f) z =  INFINITY;
    float smp = fminf(fmaxf(fmaf(ss, z, ls), 0.1f), 3.9f);

    #pragma unroll
    for (int k = 0; k < KM; ++k) {
        float invs = rcpf_(sg[k]);
        float zc = (smp - lc[k]) * invs;
        float a_ = (-lc[k]) * invs;
        float b_ = (4.0f - lc[k]) * invs;
        v2f Fz = ndtr2_f((v2f){b_, a_});
        float Z  = Fz.x - Fz.y;                // >= ~0.29
        float v  = fmaf(-0.5f, zc*zc, -0.5f*LOG2PI_F) - log_(sg[k] * Z);
        lds_cc[cb][cl][k] = v;
    }
    const float SQM = 7.9267442e-04f;     // sqrt(MU/2)
    const float HLN10 = 1.1512925f;       // 0.5*ln(10)
    float em  = exp_(-HLN10 * smp);       // 10^(-smp/2)
    float emi = SQM * rcpf_(em);          // SQM*10^(+smp/2)
    if (cl == 4) {
        lds_pr[cb][0] = emi;
    } else {
        float th = x[(size_t)b*XROW + cl];
        lds_pr[cb][1+cl] = 2.0f * th * SQM * em;
        lds_pr[cb][5+cl] = emi;
    }
}

// ---------------- fused kernel (cell-mapped prep + packed fwd + atomic out) -
// prep: 320 cells over 256 threads; wave 0 does the 64 extra cells.
// fwd : lane i handles pairs (i+4k, i+4k+25), k<6, as 3 quad-evals {k,k+3};
//       leftover pair (24,49) handled by WAVE 1 (wave 0 is prep-heavy).
// out : one atomicAdd per block (harness zeroes out[] before each launch).
__global__ void __launch_bounds__(256, 4) k_bnn(
    const float* __restrict__ x, const float* __restrict__ s,
    const float* __restrict__ u_cat, const float* __restrict__ u_trunc,
    float* __restrict__ out)
{
    __shared__ float lds_cc[BPB][NL][KM];   // 6400 B
    __shared__ float lds_pr[BPB][12];       // 3072 B
    __shared__ float red0[4], red1[4];

    unsigned tid = threadIdx.x;
    unsigned bl = tid >> 2;               // 0..63
    unsigned i  = tid & 3;
    unsigned b  = blockIdx.x * BPB + bl;
    unsigned b0 = blockIdx.x * BPB;
    const float* srow = s + (size_t)b * SROW;

    // --- phase A: layer-cells (exactly 320, no waste) ---
    process_cell(tid, b0, x, s, u_cat, u_trunc, lds_cc, lds_pr);
    if (tid < NCELL - 256) {              // wave 0: cells 256..319
        process_cell(256 + tid, b0, x, s, u_cat, u_trunc, lds_cc, lds_pr);
    }
    __syncthreads();

    // --- phase B1: per-batch logsumexp (all 4 lanes compute; i==0 keeps) ---
    float lqv = 0.0f;
    {
        float cs[KM];
        #pragma unroll
        for (int k = 0; k < KM; ++k) cs[k] = 0.0f;
        #pragma unroll
        for (int l = 0; l < NL; ++l)
            #pragma unroll
            for (int k = 0; k < KM; ++k)
                cs[k] += lds_cc[bl][l][k];
        float prosq[KM]; float sqsum = 0.0f;
        #pragma unroll
        for (int k = 0; k < KM; ++k) {
            float v = srow[k*11 + 10];
            prosq[k] = v * v;
            sqsum += prosq[k];
        }
        float lsum = log_(sqsum);
        float mx = -INFINITY;
        float av[KM];
        #pragma unroll
        for (int k = 0; k < KM; ++k) {
            av[k] = log_(prosq[k]) - lsum + cs[k];
            mx = fmaxf(mx, av[k]);
        }
        float se = 0.0f;
        #pragma unroll
        for (int k = 0; k < KM; ++k) se += exp_(av[k] - mx);
        if (i == 0) lqv = mx + log_(se);
    }

    // --- phase B2: forward model, 3 quad-evals (6 pairs) per thread ---
    float pr[9];
    #pragma unroll
    for (int q = 0; q < 9; ++q) pr[q] = lds_pr[bl][q];
    const float* oAr = x + (size_t)b * XROW + NL;
    const float* oPr = oAr + MF;

    float ex0 = fmaf((float)i, 0.10204082f, -2.0f);
    v2f c5 = {5.1026102f - ex0, 5.1026102f - ex0 - 2.5510204f};
    v2f sw = {2.5066283f * exp_(1.1512925f * ex0),
              2.5066283f * exp_(1.1512925f * (ex0 + 2.5510204f))};
    const float SWP[6] = {1.0f, 1.5998587f, 2.5595479f,
                          4.0949150f, 6.5512855f, 10.4811311f};
    const float C5P[6] = {0.0f, 0.40816327f, 0.81632653f,
                          1.2244898f, 1.6326531f, 2.0408163f};
    float ll = 0.0f;
    #pragma unroll
    for (int q = 0; q < 3; ++q) {
        int m  = (int)i + 4*q;          // pairs (m, m+25)
        int m2 = m + 12;                // pairs (m+12, m+37)
        v2f oAa = {oAr[m],  oAr[m+25]};
        v2f oPa = {oPr[m],  oPr[m+25]};
        v2f oAb = {oAr[m2], oAr[m2+25]};
        v2f oPb = {oPr[m2], oPr[m2+25]};
        ll += fwd_eval2x2(c5 - C5P[q],   sw * SWP[q],   oAa, oPa,
                          c5 - C5P[q+3], sw * SWP[q+3], oAb, oPb, pr);
    }
    // leftover pair (24, 49): WAVE 1 covers the block's 64 batches
    if (tid >= 64 && tid < 128) {
        unsigned bt = b0 + (tid & 63);
        float prt[9];
        #pragma unroll
        for (int q = 0; q < 9; ++q) prt[q] = lds_pr[tid & 63][q];
        const float* xa = x + (size_t)bt * XROW + NL;
        float e24 = fmaf(24.0f, 0.10204082f, -2.0f);
        float e49 = fmaf(49.0f, 0.10204082f, -2.0f);
        v2f c5t = {5.1026102f - e24, 5.1026102f - e49};
        v2f swt = {2.5066283f * exp_(1.1512925f * e24),
                   2.5066283f * exp_(1.1512925f * e49)};
        v2f oAt = {xa[24], xa[49]};
        v2f oPt = {xa[MF + 24], xa[MF + 49]};
        ll += fwd_eval2(c5t, swt, oAt, oPt, prt);
    }

    #pragma unroll
    for (int off = 32; off > 0; off >>= 1) {
        ll  += __shfl_down(ll,  off, 64);
        lqv += __shfl_down(lqv, off, 64);
    }
    if ((tid & 63) == 0) {
        red0[tid >> 6] = ll;
        red1[tid >> 6] = lqv;
    }
    __syncthreads();
    if (tid == 0) {
        float llb = red0[0] + red0[1] + red0[2] + red0[3];
        float lqb = red1[0] + red1[1] + red1[2] + red1[3];
        // term_lik contribution: -llb / (BATCH*2*MF) = -llb/13107200
        // term_q   contribution: +lqb / BATCH       = +lqb/131072 (2^-17 exact)
        float val = fmaf(llb, -7.62939453125e-8f, lqb * 7.62939453125e-6f);
        if (blockIdx.x == 0) val += 1.3862944f;   // + log 4
        atomicAdd(out, val);
    }
}

extern "C" void kernel_launch(void* const* d_in, const int* in_sizes, int n_in,
                              void* d_out, int out_size, void* d_ws, size_t ws_size,
                              hipStream_t stream)
{
    (void)in_sizes; (void)n_in; (void)out_size; (void)d_ws; (void)ws_size;
    const float* x       = (const float*)d_in[0];
    const float* s       = (const float*)d_in[1];
    const float* u_cat   = (const float*)d_in[2];
    const float* u_trunc = (const float*)d_in[3];
    float* out = (float*)d_out;

    k_bnn<<<NB_FUSED, 256, 0, stream>>>(x, s, u_cat, u_trunc, out);
}